// Round 1
// baseline (13866.096 us; speedup 1.0000x reference)
//
#include <hip/hip_runtime.h>
#include <hip/hip_bf16.h>
#include <math.h>

#define S 2304
#define HDIM 1152
#define NHEAD 16
#define HD 72
#define INTER 4304
#define DEPTH 4
#define MERGED 4608
#define OUTD 2048
#define KIN 1536

// ---------- helpers ----------
__device__ __forceinline__ int pos_id_of(int s) {
  int a = s / 96;
  int r = s % 96;
  int b = r >> 2;
  int c = (r >> 1) & 1;
  int d = r & 1;
  return a * 96 + c * 48 + b * 2 + d;
}

__device__ __forceinline__ float gelu_f(float v) {
  const float c = 0.7978845608028654f;
  float t = tanhf(c * (v + 0.044715f * v * v * v));
  return 0.5f * v * (1.f + t);
}

// ---------- generic NT GEMM: C[i][j] = act(sum_k A[i][k]*B[j][k] + bias[j]) (+resid) ----------
#define GT 64
#define GKT 16
#define GPAD 69

__global__ void __launch_bounds__(256) gemm_nt_kernel(
    const float* __restrict__ A, const float* __restrict__ B,
    const float* __restrict__ bias, const float* __restrict__ resid,
    float* __restrict__ C, int M, int N, int K, int act)
{
  __shared__ float As[GKT][GPAD];
  __shared__ float Bs[GKT][GPAD];
  const int tid = threadIdx.x;
  const int tm = tid >> 4;        // 0..15
  const int tn = tid & 15;        // 0..15
  const int bm = blockIdx.y * GT;
  const int bn = blockIdx.x * GT;
  const int lr = tid >> 2;        // 0..63
  const int lc = (tid & 3) << 2;  // 0,4,8,12
  float acc[4][4] = {};

  const float* Arow = A + (size_t)(bm + lr) * K;
  const bool bvalid = (bn + lr) < N;
  const float* Brow = B + (size_t)(bvalid ? (bn + lr) : 0) * K;

  for (int k0 = 0; k0 < K; k0 += GKT) {
    float4 av = *(const float4*)(Arow + k0 + lc);
    float4 bv = make_float4(0.f, 0.f, 0.f, 0.f);
    if (bvalid) bv = *(const float4*)(Brow + k0 + lc);
    As[lc + 0][lr] = av.x; As[lc + 1][lr] = av.y; As[lc + 2][lr] = av.z; As[lc + 3][lr] = av.w;
    Bs[lc + 0][lr] = bv.x; Bs[lc + 1][lr] = bv.y; Bs[lc + 2][lr] = bv.z; Bs[lc + 3][lr] = bv.w;
    __syncthreads();
#pragma unroll
    for (int kk = 0; kk < GKT; ++kk) {
      float a0 = As[kk][tm * 4 + 0], a1 = As[kk][tm * 4 + 1];
      float a2 = As[kk][tm * 4 + 2], a3 = As[kk][tm * 4 + 3];
      float b0 = Bs[kk][tn * 4 + 0], b1 = Bs[kk][tn * 4 + 1];
      float b2 = Bs[kk][tn * 4 + 2], b3 = Bs[kk][tn * 4 + 3];
      acc[0][0] += a0 * b0; acc[0][1] += a0 * b1; acc[0][2] += a0 * b2; acc[0][3] += a0 * b3;
      acc[1][0] += a1 * b0; acc[1][1] += a1 * b1; acc[1][2] += a1 * b2; acc[1][3] += a1 * b3;
      acc[2][0] += a2 * b0; acc[2][1] += a2 * b1; acc[2][2] += a2 * b2; acc[2][3] += a2 * b3;
      acc[3][0] += a3 * b0; acc[3][1] += a3 * b1; acc[3][2] += a3 * b2; acc[3][3] += a3 * b3;
    }
    __syncthreads();
  }
#pragma unroll
  for (int i = 0; i < 4; ++i) {
    int rrow = bm + tm * 4 + i;
#pragma unroll
    for (int j = 0; j < 4; ++j) {
      int ccol = bn + tn * 4 + j;
      if (ccol < N) {
        float v = acc[i][j] + bias[ccol];
        if (act == 1) v = gelu_f(v);
        if (resid) v += resid[(size_t)rrow * N + ccol];
        C[(size_t)rrow * N + ccol] = v;
      }
    }
  }
}

// ---------- LayerNorm (row = 1152) ----------
__global__ void __launch_bounds__(256) ln_kernel(const float* __restrict__ xin,
    const float* __restrict__ w, const float* __restrict__ b, float* __restrict__ out)
{
  __shared__ float red[8];
  const int row = blockIdx.x;
  const float* xr = xin + (size_t)row * HDIM;
  float s = 0.f;
  for (int i = threadIdx.x; i < HDIM; i += 256) s += xr[i];
#pragma unroll
  for (int off = 32; off > 0; off >>= 1) s += __shfl_down(s, off);
  if ((threadIdx.x & 63) == 0) red[threadIdx.x >> 6] = s;
  __syncthreads();
  float mean = (red[0] + red[1] + red[2] + red[3]) * (1.f / HDIM);
  float s2 = 0.f;
  for (int i = threadIdx.x; i < HDIM; i += 256) { float d = xr[i] - mean; s2 += d * d; }
#pragma unroll
  for (int off = 32; off > 0; off >>= 1) s2 += __shfl_down(s2, off);
  __syncthreads();
  if ((threadIdx.x & 63) == 0) red[threadIdx.x >> 6] = s2;
  __syncthreads();
  float var = (red[0] + red[1] + red[2] + red[3]) * (1.f / HDIM);
  float rstd = rsqrtf(var + 1e-6f);
  for (int i = threadIdx.x; i < HDIM; i += 256)
    out[(size_t)row * HDIM + i] = w[i] * ((xr[i] - mean) * rstd) + b[i];
}

// ---------- pos embedding add ----------
__global__ void __launch_bounds__(256) add_pos_kernel(float* __restrict__ x, const float* __restrict__ pos_tab)
{
  int s = blockIdx.x;
  int pid = pos_id_of(s);
  const float* pr = pos_tab + (size_t)pid * HDIM;
  float* xr = x + (size_t)s * HDIM;
  for (int i = threadIdx.x; i < HDIM; i += 256) xr[i] += pr[i];
}

// ---------- RoPE tables (36 cos/sin per token) ----------
__global__ void rope_tables_kernel(float* __restrict__ cosT, float* __restrict__ sinT)
{
  int s = blockIdx.x;
  int j = threadIdx.x;
  if (j >= 36) return;
  int pid = pos_id_of(s);
  float hp = (float)(pid / 48);
  float wp = (float)(pid % 48);
  int f = (j < 18) ? j : (j - 18);
  float inv = powf(10000.f, -(2.f * (float)f) / 36.f);
  float ang = ((j < 18) ? hp : wp) * inv;
  cosT[s * 36 + j] = cosf(ang);
  sinT[s * 36 + j] = sinf(ang);
}

// ---------- seg ids from cu_seqlens ----------
__global__ void seg_kernel(const int* __restrict__ cu, int n_cu, int* __restrict__ seg)
{
  int i = blockIdx.x * 256 + threadIdx.x;
  if (i >= S) return;
  int s = 0;
  for (int t = 0; t < n_cu; ++t) s += (cu[t] <= i) ? 1 : 0;
  seg[i] = s;
}

// ---------- RoPE apply in-place on q,k of qkv (S,3,NH,HD) ----------
__global__ void __launch_bounds__(256) rope_kernel(float* __restrict__ qkv,
    const float* __restrict__ cosT, const float* __restrict__ sinT)
{
  int idx = blockIdx.x * 256 + threadIdx.x;
  int d = idx % 36; int t = idx / 36;
  int hh = t % NHEAD; t /= NHEAD;
  int qk = t & 1; int s = t >> 1;
  float* base = qkv + (size_t)s * 3456 + qk * 1152 + hh * 72;
  float c = cosT[s * 36 + d], sn = sinT[s * 36 + d];
  float x0 = base[d], x1 = base[d + 36];
  base[d] = x0 * c - x1 * sn;
  base[d + 36] = x1 * c + x0 * sn;
}

// ---------- flash attention: 64-query tile per block, one head per blockIdx.y ----------
#define QT 64
#define KT2 32
#define FP 73

__global__ void __launch_bounds__(256) flash_kernel(const float* __restrict__ qkv,
    float* __restrict__ oout, const int* __restrict__ seg)
{
  __shared__ float Qs[QT][FP];
  __shared__ float Ks[KT2][FP];
  __shared__ float Vs[KT2][FP];
  __shared__ float Ps[QT][33];
  __shared__ float Al[QT];
  const int hh = blockIdx.y;
  const int q0 = blockIdx.x * QT;
  const int tid = threadIdx.x;
  // QK mapping: 4 threads per query row
  const int row = tid >> 2;
  const int sub = tid & 3;
  // PV mapping: 2 rows x 9 dims per thread
  const int rp = tid >> 3;   // 0..31
  const int dp = tid & 7;    // 0..7

  float o[2][9] = {};
  float m = -1e30f, l = 0.f;

  for (int i = tid; i < QT * HD; i += 256) {
    int r = i / HD, d = i % HD;
    Qs[r][d] = qkv[(size_t)(q0 + r) * 3456 + hh * HD + d];
  }
  const int my_seg = seg[q0 + row];
  __syncthreads();

  for (int k0 = 0; k0 < S; k0 += KT2) {
    for (int i = tid; i < KT2 * HD; i += 256) {
      int r = i / HD, d = i % HD;
      size_t base = (size_t)(k0 + r) * 3456 + hh * HD + d;
      Ks[r][d] = qkv[base + 1152];
      Vs[r][d] = qkv[base + 2304];
    }
    __syncthreads();

    float sc[8];
#pragma unroll
    for (int jj = 0; jj < 8; ++jj) sc[jj] = 0.f;
#pragma unroll 8
    for (int d = 0; d < HD; ++d) {
      float qv = Qs[row][d];
#pragma unroll
      for (int jj = 0; jj < 8; ++jj) sc[jj] += qv * Ks[sub * 8 + jj][d];
    }
    float mx = -1e30f;
#pragma unroll
    for (int jj = 0; jj < 8; ++jj) {
      int kidx = k0 + sub * 8 + jj;
      sc[jj] = sc[jj] * 0.11785113019775793f + ((seg[kidx] == my_seg) ? 0.f : -1e9f);
      mx = fmaxf(mx, sc[jj]);
    }
    mx = fmaxf(mx, __shfl_xor(mx, 1));
    mx = fmaxf(mx, __shfl_xor(mx, 2));
    float m_new = fmaxf(m, mx);
    float alpha = __expf(m - m_new);
    float ps = 0.f;
    float p[8];
#pragma unroll
    for (int jj = 0; jj < 8; ++jj) { p[jj] = __expf(sc[jj] - m_new); ps += p[jj]; }
    ps += __shfl_xor(ps, 1);
    ps += __shfl_xor(ps, 2);
    l = l * alpha + ps;
    m = m_new;
#pragma unroll
    for (int jj = 0; jj < 8; ++jj) Ps[row][sub * 8 + jj] = p[jj];
    if (sub == 0) Al[row] = alpha;
    __syncthreads();

    float al0 = Al[rp * 2], al1 = Al[rp * 2 + 1];
#pragma unroll
    for (int d = 0; d < 9; ++d) { o[0][d] *= al0; o[1][d] *= al1; }
    for (int j = 0; j < KT2; ++j) {
      float p0 = Ps[rp * 2][j], p1 = Ps[rp * 2 + 1][j];
#pragma unroll
      for (int d = 0; d < 9; ++d) {
        float vv = Vs[j][dp * 9 + d];
        o[0][d] += p0 * vv;
        o[1][d] += p1 * vv;
      }
    }
    __syncthreads();
  }

  if (sub == 0) Al[row] = l;
  __syncthreads();
  float r0 = 1.f / Al[rp * 2], r1 = 1.f / Al[rp * 2 + 1];
#pragma unroll
  for (int d = 0; d < 9; ++d) {
    oout[(size_t)(q0 + rp * 2 + 0) * HDIM + hh * HD + dp * 9 + d] = o[0][d] * r0;
    oout[(size_t)(q0 + rp * 2 + 1) * HDIM + hh * HD + dp * 9 + d] = o[1][d] * r1;
  }
}

// ---------- launch ----------
extern "C" void kernel_launch(void* const* d_in, const int* in_sizes, int n_in,
                              void* d_out, int out_size, void* d_ws, size_t ws_size,
                              hipStream_t stream)
{
  (void)n_in; (void)out_size; (void)ws_size;
  const float* pix    = (const float*)d_in[0];
  const int*   cu     = (const int*)d_in[1];
  const int    n_cu   = in_sizes[1];
  const float* conv_w = (const float*)d_in[2];
  const float* conv_b = (const float*)d_in[3];
  const float* pos_tab= (const float*)d_in[4];
  const float* ln1_w  = (const float*)d_in[5];
  const float* ln1_b  = (const float*)d_in[6];
  const float* ln2_w  = (const float*)d_in[7];
  const float* ln2_b  = (const float*)d_in[8];
  const float* qkv_w  = (const float*)d_in[9];
  const float* qkv_b  = (const float*)d_in[10];
  const float* proj_w = (const float*)d_in[11];
  const float* proj_b = (const float*)d_in[12];
  const float* fc1_w  = (const float*)d_in[13];
  const float* fc1_b  = (const float*)d_in[14];
  const float* fc2_w  = (const float*)d_in[15];
  const float* fc2_b  = (const float*)d_in[16];
  const float* mn_w   = (const float*)d_in[17];
  const float* mn_b   = (const float*)d_in[18];
  const float* mf1_w  = (const float*)d_in[19];
  const float* mf1_b  = (const float*)d_in[20];
  const float* mf2_w  = (const float*)d_in[21];
  const float* mf2_b  = (const float*)d_in[22];
  float* out = (float*)d_out;

  float* x    = (float*)d_ws;
  float* h    = x + (size_t)S * HDIM;
  float* A    = h + (size_t)S * HDIM;            // shared scratch: qkv / mlp / merger-hidden
  float* cosT = A + (size_t)S * INTER;
  float* sinT = cosT + (size_t)S * 36;
  int*   seg  = (int*)(sinT + (size_t)S * 36);

  // patch embed + pos
  gemm_nt_kernel<<<dim3(HDIM / 64, S / 64), 256, 0, stream>>>(pix, conv_w, conv_b, nullptr, x, S, HDIM, KIN, 0);
  add_pos_kernel<<<S, 256, 0, stream>>>(x, pos_tab);
  rope_tables_kernel<<<S, 64, 0, stream>>>(cosT, sinT);
  seg_kernel<<<(S + 255) / 256, 256, 0, stream>>>(cu, n_cu, seg);

  for (int layer = 0; layer < DEPTH; ++layer) {
    ln_kernel<<<S, 256, 0, stream>>>(x, ln1_w + layer * HDIM, ln1_b + layer * HDIM, h);
    gemm_nt_kernel<<<dim3(3456 / 64, S / 64), 256, 0, stream>>>(
        h, qkv_w + (size_t)layer * 3456 * HDIM, qkv_b + layer * 3456, nullptr, A, S, 3456, HDIM, 0);
    rope_kernel<<<(S * 2 * NHEAD * 36) / 256, 256, 0, stream>>>(A, cosT, sinT);
    flash_kernel<<<dim3(S / QT, NHEAD), 256, 0, stream>>>(A, h, seg);
    gemm_nt_kernel<<<dim3(HDIM / 64, S / 64), 256, 0, stream>>>(
        h, proj_w + (size_t)layer * HDIM * HDIM, proj_b + layer * HDIM, x, x, S, HDIM, HDIM, 0);
    ln_kernel<<<S, 256, 0, stream>>>(x, ln2_w + layer * HDIM, ln2_b + layer * HDIM, h);
    gemm_nt_kernel<<<dim3((INTER + 63) / 64, S / 64), 256, 0, stream>>>(
        h, fc1_w + (size_t)layer * INTER * HDIM, fc1_b + layer * INTER, nullptr, A, S, INTER, HDIM, 1);
    gemm_nt_kernel<<<dim3(HDIM / 64, S / 64), 256, 0, stream>>>(
        A, fc2_w + (size_t)layer * HDIM * INTER, fc2_b + layer * HDIM, x, x, S, HDIM, INTER, 0);
  }

  // merger
  ln_kernel<<<S, 256, 0, stream>>>(x, mn_w, mn_b, h);   // h is (576, 4608) flat
  gemm_nt_kernel<<<dim3(MERGED / 64, 576 / 64), 256, 0, stream>>>(h, mf1_w, mf1_b, nullptr, A, 576, MERGED, MERGED, 1);
  gemm_nt_kernel<<<dim3(OUTD / 64, 576 / 64), 256, 0, stream>>>(A, mf2_w, mf2_b, nullptr, out, 576, OUTD, MERGED, 0);
}

// Round 2
// 8791.245 us; speedup vs baseline: 1.5773x; 1.5773x over previous
//
#include <hip/hip_runtime.h>
#include <hip/hip_bf16.h>
#include <math.h>

#define S 2304
#define HDIM 1152
#define NHEAD 16
#define HD 72
#define INTER 4304
#define INTERP 4352   // INTER padded to multiple of 128 (and 32)
#define DEPTH 4
#define MERGED 4608
#define OUTD 2048
#define KIN 1536

typedef float f4 __attribute__((ext_vector_type(4)));
typedef short s8v __attribute__((ext_vector_type(8)));

// ---------- helpers ----------
__device__ __forceinline__ int pos_id_of(int s) {
  int a = s / 96;
  int r = s % 96;
  int b = r >> 2;
  int c = (r >> 1) & 1;
  int d = r & 1;
  return a * 96 + c * 48 + b * 2 + d;
}

__device__ __forceinline__ float gelu_f(float v) {
  const float c = 0.7978845608028654f;
  float t = tanhf(c * (v + 0.044715f * v * v * v));
  return 0.5f * v * (1.f + t);
}

// fp32 -> bf16 bits, round-to-nearest-even
__device__ __forceinline__ unsigned short f2b(float f) {
  unsigned int u = __float_as_uint(f);
  u += 0x7fffu + ((u >> 16) & 1u);
  return (unsigned short)(u >> 16);
}

// ---------- bf16 MFMA NT GEMM ----------
// C[r][c] = epilogue( sum_k A[r][k] * B[c][k] + bias[c] )
// A fp32 [M][lda] (clamped rows), B fp32 [Nreal][ldb] (k >= Kreal reads as 0),
// C fp32 [*][ldc=Nalloc]. act=1 -> gelu. cols >= Nreal are written as 0.
#define BMT 128
#define BNT 128
#define LDSP 40   // padded LDS row stride in bf16 elems (80B: 2-way bank alias only)

__global__ void __launch_bounds__(256) gemm_bf16_kernel(
    const float* __restrict__ Ap, const float* __restrict__ Bp,
    const float* __restrict__ bias, const float* __restrict__ resid,
    float* __restrict__ C, int M, int Nreal, int Kloop, int Kreal,
    int lda, int ldb, int ldc, int act)
{
  __shared__ unsigned short Asm[BMT * LDSP];
  __shared__ unsigned short Bsm[BNT * LDSP];
  const int tid = threadIdx.x;
  const int lane = tid & 63;
  const int wv = tid >> 6;
  const int wr = wv >> 1;          // wave row 0..1
  const int wc = wv & 1;           // wave col 0..1
  const int bm = blockIdx.y * BMT;
  const int bn = blockIdx.x * BNT;

  f4 acc[4][4];
#pragma unroll
  for (int m = 0; m < 4; ++m)
#pragma unroll
    for (int n = 0; n < 4; ++n) { acc[m][n].x = 0.f; acc[m][n].y = 0.f; acc[m][n].z = 0.f; acc[m][n].w = 0.f; }

  const int srow = tid >> 3;        // staging: 0..31 within quarter
  const int skk = (tid & 7) << 2;   // 0,4,...,28
  const int lk = (lane >> 4) << 3;  // fragment k-offset: 0,8,16,24
  const int lr = lane & 15;         // fragment row/col within 16

  for (int k0 = 0; k0 < Kloop; k0 += 32) {
#pragma unroll
    for (int c = 0; c < 4; ++c) {
      int row = c * 32 + srow;
      // A stage
      int ar = bm + row; if (ar >= M) ar = M - 1;
      float4 av = *(const float4*)(Ap + (size_t)ar * lda + k0 + skk);
      ushort4 au;
      au.x = f2b(av.x); au.y = f2b(av.y); au.z = f2b(av.z); au.w = f2b(av.w);
      *(ushort4*)(&Asm[row * LDSP + skk]) = au;
      // B stage
      int br = bn + row; if (br >= Nreal) br = Nreal - 1;
      float4 bv = make_float4(0.f, 0.f, 0.f, 0.f);
      if (k0 + skk < Kreal) bv = *(const float4*)(Bp + (size_t)br * ldb + k0 + skk);
      ushort4 bu;
      bu.x = f2b(bv.x); bu.y = f2b(bv.y); bu.z = f2b(bv.z); bu.w = f2b(bv.w);
      *(ushort4*)(&Bsm[row * LDSP + skk]) = bu;
    }
    __syncthreads();
    s8v af[4], bf[4];
#pragma unroll
    for (int m = 0; m < 4; ++m)
      af[m] = *reinterpret_cast<const s8v*>(&Asm[(wr * 64 + m * 16 + lr) * LDSP + lk]);
#pragma unroll
    for (int n = 0; n < 4; ++n)
      bf[n] = *reinterpret_cast<const s8v*>(&Bsm[(wc * 64 + n * 16 + lr) * LDSP + lk]);
#pragma unroll
    for (int m = 0; m < 4; ++m)
#pragma unroll
      for (int n = 0; n < 4; ++n)
        acc[m][n] = __builtin_amdgcn_mfma_f32_16x16x32_bf16(af[m], bf[n], acc[m][n], 0, 0, 0);
    __syncthreads();
  }

#pragma unroll
  for (int m = 0; m < 4; ++m) {
#pragma unroll
    for (int n = 0; n < 4; ++n) {
      int cidx = bn + wc * 64 + n * 16 + lr;
      float bb = (cidx < Nreal) ? bias[cidx] : 0.f;
#pragma unroll
      for (int j = 0; j < 4; ++j) {
        int r = bm + wr * 64 + m * 16 + ((lane >> 4) << 2) + j;
        if (r < M) {
          float v = acc[m][n][j] + bb;
          if (act == 1) v = gelu_f(v);
          if (cidx >= Nreal) v = 0.f;
          if (resid) v += resid[(size_t)r * ldc + cidx];
          C[(size_t)r * ldc + cidx] = v;
        }
      }
    }
  }
}

// ---------- fp32 NT GEMM (kept for final merger fc2 only) ----------
#define GT 64
#define GKT 16
#define GPAD 69

__global__ void __launch_bounds__(256) gemm_nt_kernel(
    const float* __restrict__ A, const float* __restrict__ B,
    const float* __restrict__ bias, const float* __restrict__ resid,
    float* __restrict__ C, int M, int N, int K, int act)
{
  __shared__ float As[GKT][GPAD];
  __shared__ float Bs[GKT][GPAD];
  const int tid = threadIdx.x;
  const int tm = tid >> 4;
  const int tn = tid & 15;
  const int bm = blockIdx.y * GT;
  const int bn = blockIdx.x * GT;
  const int lr = tid >> 2;
  const int lc = (tid & 3) << 2;
  float acc[4][4] = {};

  const float* Arow = A + (size_t)(bm + lr) * K;
  const bool bvalid = (bn + lr) < N;
  const float* Brow = B + (size_t)(bvalid ? (bn + lr) : 0) * K;

  for (int k0 = 0; k0 < K; k0 += GKT) {
    float4 av = *(const float4*)(Arow + k0 + lc);
    float4 bv = make_float4(0.f, 0.f, 0.f, 0.f);
    if (bvalid) bv = *(const float4*)(Brow + k0 + lc);
    As[lc + 0][lr] = av.x; As[lc + 1][lr] = av.y; As[lc + 2][lr] = av.z; As[lc + 3][lr] = av.w;
    Bs[lc + 0][lr] = bv.x; Bs[lc + 1][lr] = bv.y; Bs[lc + 2][lr] = bv.z; Bs[lc + 3][lr] = bv.w;
    __syncthreads();
#pragma unroll
    for (int kk = 0; kk < GKT; ++kk) {
      float a0 = As[kk][tm * 4 + 0], a1 = As[kk][tm * 4 + 1];
      float a2 = As[kk][tm * 4 + 2], a3 = As[kk][tm * 4 + 3];
      float b0 = Bs[kk][tn * 4 + 0], b1 = Bs[kk][tn * 4 + 1];
      float b2 = Bs[kk][tn * 4 + 2], b3 = Bs[kk][tn * 4 + 3];
      acc[0][0] += a0 * b0; acc[0][1] += a0 * b1; acc[0][2] += a0 * b2; acc[0][3] += a0 * b3;
      acc[1][0] += a1 * b0; acc[1][1] += a1 * b1; acc[1][2] += a1 * b2; acc[1][3] += a1 * b3;
      acc[2][0] += a2 * b0; acc[2][1] += a2 * b1; acc[2][2] += a2 * b2; acc[2][3] += a2 * b3;
      acc[3][0] += a3 * b0; acc[3][1] += a3 * b1; acc[3][2] += a3 * b2; acc[3][3] += a3 * b3;
    }
    __syncthreads();
  }
#pragma unroll
  for (int i = 0; i < 4; ++i) {
    int rrow = bm + tm * 4 + i;
#pragma unroll
    for (int j = 0; j < 4; ++j) {
      int ccol = bn + tn * 4 + j;
      if (ccol < N) {
        float v = acc[i][j] + bias[ccol];
        if (act == 1) v = gelu_f(v);
        if (resid) v += resid[(size_t)rrow * N + ccol];
        C[(size_t)rrow * N + ccol] = v;
      }
    }
  }
}

// ---------- LayerNorm (row = 1152) ----------
__global__ void __launch_bounds__(256) ln_kernel(const float* __restrict__ xin,
    const float* __restrict__ w, const float* __restrict__ b, float* __restrict__ out)
{
  __shared__ float red[8];
  const int row = blockIdx.x;
  const float* xr = xin + (size_t)row * HDIM;
  float s = 0.f;
  for (int i = threadIdx.x; i < HDIM; i += 256) s += xr[i];
#pragma unroll
  for (int off = 32; off > 0; off >>= 1) s += __shfl_down(s, off);
  if ((threadIdx.x & 63) == 0) red[threadIdx.x >> 6] = s;
  __syncthreads();
  float mean = (red[0] + red[1] + red[2] + red[3]) * (1.f / HDIM);
  float s2 = 0.f;
  for (int i = threadIdx.x; i < HDIM; i += 256) { float d = xr[i] - mean; s2 += d * d; }
#pragma unroll
  for (int off = 32; off > 0; off >>= 1) s2 += __shfl_down(s2, off);
  __syncthreads();
  if ((threadIdx.x & 63) == 0) red[threadIdx.x >> 6] = s2;
  __syncthreads();
  float var = (red[0] + red[1] + red[2] + red[3]) * (1.f / HDIM);
  float rstd = rsqrtf(var + 1e-6f);
  for (int i = threadIdx.x; i < HDIM; i += 256)
    out[(size_t)row * HDIM + i] = w[i] * ((xr[i] - mean) * rstd) + b[i];
}

// ---------- pos embedding add ----------
__global__ void __launch_bounds__(256) add_pos_kernel(float* __restrict__ x, const float* __restrict__ pos_tab)
{
  int s = blockIdx.x;
  int pid = pos_id_of(s);
  const float* pr = pos_tab + (size_t)pid * HDIM;
  float* xr = x + (size_t)s * HDIM;
  for (int i = threadIdx.x; i < HDIM; i += 256) xr[i] += pr[i];
}

// ---------- RoPE tables ----------
__global__ void rope_tables_kernel(float* __restrict__ cosT, float* __restrict__ sinT)
{
  int s = blockIdx.x;
  int j = threadIdx.x;
  if (j >= 36) return;
  int pid = pos_id_of(s);
  float hp = (float)(pid / 48);
  float wp = (float)(pid % 48);
  int f = (j < 18) ? j : (j - 18);
  float inv = powf(10000.f, -(2.f * (float)f) / 36.f);
  float ang = ((j < 18) ? hp : wp) * inv;
  cosT[s * 36 + j] = cosf(ang);
  sinT[s * 36 + j] = sinf(ang);
}

// ---------- seg ids ----------
__global__ void seg_kernel(const int* __restrict__ cu, int n_cu, int* __restrict__ seg)
{
  int i = blockIdx.x * 256 + threadIdx.x;
  if (i >= S) return;
  int s = 0;
  for (int t = 0; t < n_cu; ++t) s += (cu[t] <= i) ? 1 : 0;
  seg[i] = s;
}

// ---------- RoPE apply ----------
__global__ void __launch_bounds__(256) rope_kernel(float* __restrict__ qkv,
    const float* __restrict__ cosT, const float* __restrict__ sinT)
{
  int idx = blockIdx.x * 256 + threadIdx.x;
  int d = idx % 36; int t = idx / 36;
  int hh = t % NHEAD; t /= NHEAD;
  int qk = t & 1; int s = t >> 1;
  float* base = qkv + (size_t)s * 3456 + qk * 1152 + hh * 72;
  float c = cosT[s * 36 + d], sn = sinT[s * 36 + d];
  float x0 = base[d], x1 = base[d + 36];
  base[d] = x0 * c - x1 * sn;
  base[d + 36] = x1 * c + x0 * sn;
}

// ---------- flash attention: 32-query tile, 8 threads/row ----------
#define QT 32
#define KT2 32
#define FP 73

__global__ void __launch_bounds__(256) flash_kernel(const float* __restrict__ qkv,
    float* __restrict__ oout, const int* __restrict__ seg)
{
  __shared__ float Qs[QT][FP];
  __shared__ float Ks[KT2][FP];
  __shared__ float Vs[KT2][FP];
  __shared__ float Ps[QT][33];
  __shared__ float Al[QT];
  const int hh = blockIdx.y;
  const int q0 = blockIdx.x * QT;
  const int tid = threadIdx.x;
  const int row = tid >> 3;   // 0..31
  const int sub = tid & 7;    // 0..7

  float o[9] = {};
  float m = -1e30f, l = 0.f;

  for (int i = tid; i < QT * HD; i += 256) {
    int r = i / HD, d = i % HD;
    Qs[r][d] = qkv[(size_t)(q0 + r) * 3456 + hh * HD + d];
  }
  const int my_seg = seg[q0 + row];
  __syncthreads();

  for (int k0 = 0; k0 < S; k0 += KT2) {
    for (int i = tid; i < KT2 * HD; i += 256) {
      int r = i / HD, d = i % HD;
      size_t base = (size_t)(k0 + r) * 3456 + hh * HD + d;
      Ks[r][d] = qkv[base + 1152];
      Vs[r][d] = qkv[base + 2304];
    }
    __syncthreads();

    float sc[4] = {0.f, 0.f, 0.f, 0.f};
#pragma unroll 8
    for (int d = 0; d < HD; ++d) {
      float qv = Qs[row][d];
#pragma unroll
      for (int jj = 0; jj < 4; ++jj) sc[jj] += qv * Ks[sub * 4 + jj][d];
    }
    float mx = -1e30f;
#pragma unroll
    for (int jj = 0; jj < 4; ++jj) {
      int kidx = k0 + sub * 4 + jj;
      sc[jj] = sc[jj] * 0.11785113019775793f + ((seg[kidx] == my_seg) ? 0.f : -1e9f);
      mx = fmaxf(mx, sc[jj]);
    }
    mx = fmaxf(mx, __shfl_xor(mx, 1));
    mx = fmaxf(mx, __shfl_xor(mx, 2));
    mx = fmaxf(mx, __shfl_xor(mx, 4));
    float m_new = fmaxf(m, mx);
    float alpha = __expf(m - m_new);
    float p[4];
    float ps = 0.f;
#pragma unroll
    for (int jj = 0; jj < 4; ++jj) { p[jj] = __expf(sc[jj] - m_new); ps += p[jj]; }
    ps += __shfl_xor(ps, 1);
    ps += __shfl_xor(ps, 2);
    ps += __shfl_xor(ps, 4);
    l = l * alpha + ps;
    m = m_new;
#pragma unroll
    for (int jj = 0; jj < 4; ++jj) Ps[row][sub * 4 + jj] = p[jj];
    if (sub == 0) Al[row] = alpha;
    __syncthreads();

    float alr = Al[row];
#pragma unroll
    for (int d = 0; d < 9; ++d) o[d] *= alr;
    for (int j = 0; j < KT2; ++j) {
      float pj = Ps[row][j];
#pragma unroll
      for (int d = 0; d < 9; ++d) o[d] += pj * Vs[j][sub * 9 + d];
    }
    __syncthreads();
  }

  if (sub == 0) Al[row] = l;
  __syncthreads();
  float rden = 1.f / Al[row];
#pragma unroll
  for (int d = 0; d < 9; ++d)
    oout[(size_t)(q0 + row) * HDIM + hh * HD + sub * 9 + d] = o[d] * rden;
}

// ---------- launch ----------
extern "C" void kernel_launch(void* const* d_in, const int* in_sizes, int n_in,
                              void* d_out, int out_size, void* d_ws, size_t ws_size,
                              hipStream_t stream)
{
  (void)n_in; (void)out_size; (void)ws_size;
  const float* pix    = (const float*)d_in[0];
  const int*   cu     = (const int*)d_in[1];
  const int    n_cu   = in_sizes[1];
  const float* conv_w = (const float*)d_in[2];
  const float* conv_b = (const float*)d_in[3];
  const float* pos_tab= (const float*)d_in[4];
  const float* ln1_w  = (const float*)d_in[5];
  const float* ln1_b  = (const float*)d_in[6];
  const float* ln2_w  = (const float*)d_in[7];
  const float* ln2_b  = (const float*)d_in[8];
  const float* qkv_w  = (const float*)d_in[9];
  const float* qkv_b  = (const float*)d_in[10];
  const float* proj_w = (const float*)d_in[11];
  const float* proj_b = (const float*)d_in[12];
  const float* fc1_w  = (const float*)d_in[13];
  const float* fc1_b  = (const float*)d_in[14];
  const float* fc2_w  = (const float*)d_in[15];
  const float* fc2_b  = (const float*)d_in[16];
  const float* mn_w   = (const float*)d_in[17];
  const float* mn_b   = (const float*)d_in[18];
  const float* mf1_w  = (const float*)d_in[19];
  const float* mf1_b  = (const float*)d_in[20];
  const float* mf2_w  = (const float*)d_in[21];
  const float* mf2_b  = (const float*)d_in[22];
  float* out = (float*)d_out;

  float* x    = (float*)d_ws;
  float* h    = x + (size_t)S * HDIM;
  float* A    = h + (size_t)S * HDIM;              // qkv (S x 3456) / fc1-out (S x 4352) / merger-hidden
  float* cosT = A + (size_t)S * INTERP;
  float* sinT = cosT + (size_t)S * 36;
  int*   seg  = (int*)(sinT + (size_t)S * 36);

  // patch embed (bf16 MFMA) + pos
  gemm_bf16_kernel<<<dim3(HDIM / 128, S / 128), 256, 0, stream>>>(
      pix, conv_w, conv_b, nullptr, x, S, HDIM, KIN, KIN, KIN, KIN, HDIM, 0);
  add_pos_kernel<<<S, 256, 0, stream>>>(x, pos_tab);
  rope_tables_kernel<<<S, 64, 0, stream>>>(cosT, sinT);
  seg_kernel<<<(S + 255) / 256, 256, 0, stream>>>(cu, n_cu, seg);

  for (int layer = 0; layer < DEPTH; ++layer) {
    ln_kernel<<<S, 256, 0, stream>>>(x, ln1_w + layer * HDIM, ln1_b + layer * HDIM, h);
    gemm_bf16_kernel<<<dim3(3456 / 128, S / 128), 256, 0, stream>>>(
        h, qkv_w + (size_t)layer * 3456 * HDIM, qkv_b + layer * 3456, nullptr, A,
        S, 3456, HDIM, HDIM, HDIM, HDIM, 3456, 0);
    rope_kernel<<<(S * 2 * NHEAD * 36) / 256, 256, 0, stream>>>(A, cosT, sinT);
    flash_kernel<<<dim3(S / QT, NHEAD), 256, 0, stream>>>(A, h, seg);
    gemm_bf16_kernel<<<dim3(HDIM / 128, S / 128), 256, 0, stream>>>(
        h, proj_w + (size_t)layer * HDIM * HDIM, proj_b + layer * HDIM, x, x,
        S, HDIM, HDIM, HDIM, HDIM, HDIM, HDIM, 0);
    ln_kernel<<<S, 256, 0, stream>>>(x, ln2_w + layer * HDIM, ln2_b + layer * HDIM, h);
    gemm_bf16_kernel<<<dim3(INTERP / 128, S / 128), 256, 0, stream>>>(
        h, fc1_w + (size_t)layer * INTER * HDIM, fc1_b + layer * INTER, nullptr, A,
        S, INTER, HDIM, HDIM, HDIM, HDIM, INTERP, 1);
    gemm_bf16_kernel<<<dim3(HDIM / 128, S / 128), 256, 0, stream>>>(
        A, fc2_w + (size_t)layer * HDIM * INTER, fc2_b + layer * HDIM, x, x,
        S, HDIM, INTERP, INTER, INTERP, INTER, HDIM, 0);
  }

  // merger
  ln_kernel<<<S, 256, 0, stream>>>(x, mn_w, mn_b, h);   // h viewed as (576, 4608)
  gemm_bf16_kernel<<<dim3(MERGED / 128, (576 + 127) / 128), 256, 0, stream>>>(
      h, mf1_w, mf1_b, nullptr, A, 576, MERGED, MERGED, MERGED, MERGED, MERGED, MERGED, 1);
  gemm_nt_kernel<<<dim3(OUTD / 64, 576 / 64), 256, 0, stream>>>(
      A, mf2_w, mf2_b, nullptr, out, 576, OUTD, MERGED, 0);
}

// Round 3
// 4875.491 us; speedup vs baseline: 2.8440x; 1.8032x over previous
//
#include <hip/hip_runtime.h>
#include <hip/hip_bf16.h>
#include <math.h>

#define S 2304
#define HDIM 1152
#define NHEAD 16
#define HD 72
#define INTER 4304
#define INTERP 4352   // INTER padded to multiple of 128 (and 32)
#define DEPTH 4
#define MERGED 4608
#define OUTD 2048
#define KIN 1536

typedef float f4 __attribute__((ext_vector_type(4)));
typedef short s8v __attribute__((ext_vector_type(8)));

// ---------- helpers ----------
__device__ __forceinline__ int pos_id_of(int s) {
  int a = s / 96;
  int r = s % 96;
  int b = r >> 2;
  int c = (r >> 1) & 1;
  int d = r & 1;
  return a * 96 + c * 48 + b * 2 + d;
}

__device__ __forceinline__ float gelu_f(float v) {
  const float c = 0.7978845608028654f;
  float t = tanhf(c * (v + 0.044715f * v * v * v));
  return 0.5f * v * (1.f + t);
}

// fp32 -> bf16 bits, round-to-nearest-even
__device__ __forceinline__ unsigned short f2b(float f) {
  unsigned int u = __float_as_uint(f);
  u += 0x7fffu + ((u >> 16) & 1u);
  return (unsigned short)(u >> 16);
}

// ---------- bf16 MFMA NT GEMM ----------
#define BMT 128
#define BNT 128
#define LDSP 40

__global__ void __launch_bounds__(256) gemm_bf16_kernel(
    const float* __restrict__ Ap, const float* __restrict__ Bp,
    const float* __restrict__ bias, const float* __restrict__ resid,
    float* __restrict__ C, int M, int Nreal, int Kloop, int Kreal,
    int lda, int ldb, int ldc, int act)
{
  __shared__ unsigned short Asm[BMT * LDSP];
  __shared__ unsigned short Bsm[BNT * LDSP];
  const int tid = threadIdx.x;
  const int lane = tid & 63;
  const int wv = tid >> 6;
  const int wr = wv >> 1;
  const int wc = wv & 1;
  const int bm = blockIdx.y * BMT;
  const int bn = blockIdx.x * BNT;

  f4 acc[4][4];
#pragma unroll
  for (int m = 0; m < 4; ++m)
#pragma unroll
    for (int n = 0; n < 4; ++n) { acc[m][n].x = 0.f; acc[m][n].y = 0.f; acc[m][n].z = 0.f; acc[m][n].w = 0.f; }

  const int srow = tid >> 3;
  const int skk = (tid & 7) << 2;
  const int lk = (lane >> 4) << 3;
  const int lr = lane & 15;

  for (int k0 = 0; k0 < Kloop; k0 += 32) {
#pragma unroll
    for (int c = 0; c < 4; ++c) {
      int row = c * 32 + srow;
      int ar = bm + row; if (ar >= M) ar = M - 1;
      float4 av = *(const float4*)(Ap + (size_t)ar * lda + k0 + skk);
      ushort4 au;
      au.x = f2b(av.x); au.y = f2b(av.y); au.z = f2b(av.z); au.w = f2b(av.w);
      *(ushort4*)(&Asm[row * LDSP + skk]) = au;
      int br = bn + row; if (br >= Nreal) br = Nreal - 1;
      float4 bv = make_float4(0.f, 0.f, 0.f, 0.f);
      if (k0 + skk < Kreal) bv = *(const float4*)(Bp + (size_t)br * ldb + k0 + skk);
      ushort4 bu;
      bu.x = f2b(bv.x); bu.y = f2b(bv.y); bu.z = f2b(bv.z); bu.w = f2b(bv.w);
      *(ushort4*)(&Bsm[row * LDSP + skk]) = bu;
    }
    __syncthreads();
    s8v af[4], bf[4];
#pragma unroll
    for (int m = 0; m < 4; ++m)
      af[m] = *reinterpret_cast<const s8v*>(&Asm[(wr * 64 + m * 16 + lr) * LDSP + lk]);
#pragma unroll
    for (int n = 0; n < 4; ++n)
      bf[n] = *reinterpret_cast<const s8v*>(&Bsm[(wc * 64 + n * 16 + lr) * LDSP + lk]);
#pragma unroll
    for (int m = 0; m < 4; ++m)
#pragma unroll
      for (int n = 0; n < 4; ++n)
        acc[m][n] = __builtin_amdgcn_mfma_f32_16x16x32_bf16(af[m], bf[n], acc[m][n], 0, 0, 0);
    __syncthreads();
  }

#pragma unroll
  for (int m = 0; m < 4; ++m) {
#pragma unroll
    for (int n = 0; n < 4; ++n) {
      int cidx = bn + wc * 64 + n * 16 + lr;
      float bb = (cidx < Nreal) ? bias[cidx] : 0.f;
#pragma unroll
      for (int j = 0; j < 4; ++j) {
        int r = bm + wr * 64 + m * 16 + ((lane >> 4) << 2) + j;
        if (r < M) {
          float v = acc[m][n][j] + bb;
          if (act == 1) v = gelu_f(v);
          if (cidx >= Nreal) v = 0.f;
          if (resid) v += resid[(size_t)r * ldc + cidx];
          C[(size_t)r * ldc + cidx] = v;
        }
      }
    }
  }
}

// ---------- fp32 NT GEMM (final merger fc2 only) ----------
#define GT 64
#define GKT 16
#define GPAD 69

__global__ void __launch_bounds__(256) gemm_nt_kernel(
    const float* __restrict__ A, const float* __restrict__ B,
    const float* __restrict__ bias, const float* __restrict__ resid,
    float* __restrict__ C, int M, int N, int K, int act)
{
  __shared__ float As[GKT][GPAD];
  __shared__ float Bs[GKT][GPAD];
  const int tid = threadIdx.x;
  const int tm = tid >> 4;
  const int tn = tid & 15;
  const int bm = blockIdx.y * GT;
  const int bn = blockIdx.x * GT;
  const int lr = tid >> 2;
  const int lc = (tid & 3) << 2;
  float acc[4][4] = {};

  const float* Arow = A + (size_t)(bm + lr) * K;
  const bool bvalid = (bn + lr) < N;
  const float* Brow = B + (size_t)(bvalid ? (bn + lr) : 0) * K;

  for (int k0 = 0; k0 < K; k0 += GKT) {
    float4 av = *(const float4*)(Arow + k0 + lc);
    float4 bv = make_float4(0.f, 0.f, 0.f, 0.f);
    if (bvalid) bv = *(const float4*)(Brow + k0 + lc);
    As[lc + 0][lr] = av.x; As[lc + 1][lr] = av.y; As[lc + 2][lr] = av.z; As[lc + 3][lr] = av.w;
    Bs[lc + 0][lr] = bv.x; Bs[lc + 1][lr] = bv.y; Bs[lc + 2][lr] = bv.z; Bs[lc + 3][lr] = bv.w;
    __syncthreads();
#pragma unroll
    for (int kk = 0; kk < GKT; ++kk) {
      float a0 = As[kk][tm * 4 + 0], a1 = As[kk][tm * 4 + 1];
      float a2 = As[kk][tm * 4 + 2], a3 = As[kk][tm * 4 + 3];
      float b0 = Bs[kk][tn * 4 + 0], b1 = Bs[kk][tn * 4 + 1];
      float b2 = Bs[kk][tn * 4 + 2], b3 = Bs[kk][tn * 4 + 3];
      acc[0][0] += a0 * b0; acc[0][1] += a0 * b1; acc[0][2] += a0 * b2; acc[0][3] += a0 * b3;
      acc[1][0] += a1 * b0; acc[1][1] += a1 * b1; acc[1][2] += a1 * b2; acc[1][3] += a1 * b3;
      acc[2][0] += a2 * b0; acc[2][1] += a2 * b1; acc[2][2] += a2 * b2; acc[2][3] += a2 * b3;
      acc[3][0] += a3 * b0; acc[3][1] += a3 * b1; acc[3][2] += a3 * b2; acc[3][3] += a3 * b3;
    }
    __syncthreads();
  }
#pragma unroll
  for (int i = 0; i < 4; ++i) {
    int rrow = bm + tm * 4 + i;
#pragma unroll
    for (int j = 0; j < 4; ++j) {
      int ccol = bn + tn * 4 + j;
      if (ccol < N) {
        float v = acc[i][j] + bias[ccol];
        if (act == 1) v = gelu_f(v);
        if (resid) v += resid[(size_t)rrow * N + ccol];
        C[(size_t)rrow * N + ccol] = v;
      }
    }
  }
}

// ---------- LayerNorm ----------
__global__ void __launch_bounds__(256) ln_kernel(const float* __restrict__ xin,
    const float* __restrict__ w, const float* __restrict__ b, float* __restrict__ out)
{
  __shared__ float red[8];
  const int row = blockIdx.x;
  const float* xr = xin + (size_t)row * HDIM;
  float s = 0.f;
  for (int i = threadIdx.x; i < HDIM; i += 256) s += xr[i];
#pragma unroll
  for (int off = 32; off > 0; off >>= 1) s += __shfl_down(s, off);
  if ((threadIdx.x & 63) == 0) red[threadIdx.x >> 6] = s;
  __syncthreads();
  float mean = (red[0] + red[1] + red[2] + red[3]) * (1.f / HDIM);
  float s2 = 0.f;
  for (int i = threadIdx.x; i < HDIM; i += 256) { float d = xr[i] - mean; s2 += d * d; }
#pragma unroll
  for (int off = 32; off > 0; off >>= 1) s2 += __shfl_down(s2, off);
  __syncthreads();
  if ((threadIdx.x & 63) == 0) red[threadIdx.x >> 6] = s2;
  __syncthreads();
  float var = (red[0] + red[1] + red[2] + red[3]) * (1.f / HDIM);
  float rstd = rsqrtf(var + 1e-6f);
  for (int i = threadIdx.x; i < HDIM; i += 256)
    out[(size_t)row * HDIM + i] = w[i] * ((xr[i] - mean) * rstd) + b[i];
}

// ---------- pos embedding add ----------
__global__ void __launch_bounds__(256) add_pos_kernel(float* __restrict__ x, const float* __restrict__ pos_tab)
{
  int s = blockIdx.x;
  int pid = pos_id_of(s);
  const float* pr = pos_tab + (size_t)pid * HDIM;
  float* xr = x + (size_t)s * HDIM;
  for (int i = threadIdx.x; i < HDIM; i += 256) xr[i] += pr[i];
}

// ---------- RoPE tables ----------
__global__ void rope_tables_kernel(float* __restrict__ cosT, float* __restrict__ sinT)
{
  int s = blockIdx.x;
  int j = threadIdx.x;
  if (j >= 36) return;
  int pid = pos_id_of(s);
  float hp = (float)(pid / 48);
  float wp = (float)(pid % 48);
  int f = (j < 18) ? j : (j - 18);
  float inv = powf(10000.f, -(2.f * (float)f) / 36.f);
  float ang = ((j < 18) ? hp : wp) * inv;
  cosT[s * 36 + j] = cosf(ang);
  sinT[s * 36 + j] = sinf(ang);
}

// ---------- seg ids ----------
__global__ void seg_kernel(const int* __restrict__ cu, int n_cu, int* __restrict__ seg)
{
  int i = blockIdx.x * 256 + threadIdx.x;
  if (i >= S) return;
  int s = 0;
  for (int t = 0; t < n_cu; ++t) s += (cu[t] <= i) ? 1 : 0;
  seg[i] = s;
}

// ---------- RoPE apply ----------
__global__ void __launch_bounds__(256) rope_kernel(float* __restrict__ qkv,
    const float* __restrict__ cosT, const float* __restrict__ sinT)
{
  int idx = blockIdx.x * 256 + threadIdx.x;
  int d = idx % 36; int t = idx / 36;
  int hh = t % NHEAD; t /= NHEAD;
  int qk = t & 1; int s = t >> 1;
  float* base = qkv + (size_t)s * 3456 + qk * 1152 + hh * 72;
  float c = cosT[s * 36 + d], sn = sinT[s * 36 + d];
  float x0 = base[d], x1 = base[d + 36];
  base[d] = x0 * c - x1 * sn;
  base[d + 36] = x1 * c + x0 * sn;
}

// ---------- MFMA flash attention ----------
// Block = (64 q-rows, 1 head). 4 waves; wave wv owns q-rows wv*16..wv*16+15.
// K-tile = 64 keys. HD=72 padded to 96 for QK^T (Q register pad zeroed;
// Ks pad cols zeroed once). PV: P (64 k) via per-wave LDS slice, Vt transposed.
#define KT 64
#define ASCALE 0.11785113019775793f

__global__ void __launch_bounds__(256) flash_mfma_kernel(
    const float* __restrict__ qkv, float* __restrict__ oout, const int* __restrict__ seg)
{
  __shared__ __align__(16) unsigned short Ks[64 * 104];
  __shared__ __align__(16) unsigned short Vt[80 * 72];
  __shared__ __align__(16) unsigned short Ps[4][16 * 72];

  const int tid = threadIdx.x;
  const int lane = tid & 63;
  const int wv = tid >> 6;
  const int g = lane >> 4;   // 0..3
  const int c = lane & 15;   // 0..15
  const int hh = blockIdx.y;
  const int q0 = blockIdx.x * 64;

  // one-time zeroing: Ks pad cols 72..95, Vt rows 72..79 (avoid NaN garbage)
  for (int i = tid; i < 64 * 12; i += 256) {
    int r = i / 12, cc = i % 12;
    *(unsigned int*)&Ks[r * 104 + 72 + cc * 2] = 0u;
  }
  for (int i = tid; i < 288; i += 256) {
    *(unsigned int*)&Vt[72 * 72 + i * 2] = 0u;
  }

  // Q fragments direct to registers (A-operand rows = lane&15)
  s8v qf[3];
  {
    const int qrow = q0 + wv * 16 + c;
    const float* qb = qkv + (size_t)qrow * 3456 + hh * HD;
#pragma unroll
    for (int ks = 0; ks < 3; ++ks) {
      int k = ks * 32 + g * 8;
      s8v f;
      if (k < HD) {
        float4 a = *(const float4*)(qb + k);
        float4 b = *(const float4*)(qb + k + 4);
        f[0] = (short)f2b(a.x); f[1] = (short)f2b(a.y); f[2] = (short)f2b(a.z); f[3] = (short)f2b(a.w);
        f[4] = (short)f2b(b.x); f[5] = (short)f2b(b.y); f[6] = (short)f2b(b.z); f[7] = (short)f2b(b.w);
      } else {
#pragma unroll
        for (int t = 0; t < 8; ++t) f[t] = 0;
      }
      qf[ks] = f;
    }
  }

  int msg[4];
#pragma unroll
  for (int j = 0; j < 4; ++j) msg[j] = seg[q0 + wv * 16 + g * 4 + j];

  float mj[4], lj[4];
#pragma unroll
  for (int j = 0; j < 4; ++j) { mj[j] = -1e30f; lj[j] = 0.f; }
  f4 acco[5];
#pragma unroll
  for (int n = 0; n < 5; ++n) { acco[n].x = 0.f; acco[n].y = 0.f; acco[n].z = 0.f; acco[n].w = 0.f; }

  for (int k0 = 0; k0 < S; k0 += KT) {
    __syncthreads();   // previous tile's reads done; pad zeros visible
    // stage K tile: row-major mapping (coalesced global)
    for (int idx = tid; idx < 64 * 18; idx += 256) {
      int r = idx / 18, c4 = idx % 18;
      float4 v = *(const float4*)(qkv + (size_t)(k0 + r) * 3456 + HDIM + hh * HD + c4 * 4);
      ushort4 u;
      u.x = f2b(v.x); u.y = f2b(v.y); u.z = f2b(v.z); u.w = f2b(v.w);
      *(ushort4*)&Ks[r * 104 + c4 * 4] = u;
    }
    // stage V transposed: k-major mapping (conflict-free LDS writes)
    for (int idx = tid; idx < 18 * 64; idx += 256) {
      int r = idx & 63, c4 = idx >> 6;
      float4 v = *(const float4*)(qkv + (size_t)(k0 + r) * 3456 + 2 * HDIM + hh * HD + c4 * 4);
      Vt[(c4 * 4 + 0) * 72 + r] = f2b(v.x);
      Vt[(c4 * 4 + 1) * 72 + r] = f2b(v.y);
      Vt[(c4 * 4 + 2) * 72 + r] = f2b(v.z);
      Vt[(c4 * 4 + 3) * 72 + r] = f2b(v.w);
    }
    __syncthreads();

    int sgn[4];
#pragma unroll
    for (int n = 0; n < 4; ++n) sgn[n] = seg[k0 + n * 16 + c];

    // QK^T: 4 col-frags x 3 k-steps
    f4 accs[4];
#pragma unroll
    for (int n = 0; n < 4; ++n) { accs[n].x = 0.f; accs[n].y = 0.f; accs[n].z = 0.f; accs[n].w = 0.f; }
#pragma unroll
    for (int ks = 0; ks < 3; ++ks) {
#pragma unroll
      for (int n = 0; n < 4; ++n) {
        s8v bk = *reinterpret_cast<const s8v*>(&Ks[(n * 16 + c) * 104 + ks * 32 + g * 8]);
        accs[n] = __builtin_amdgcn_mfma_f32_16x16x32_bf16(qf[ks], bk, accs[n], 0, 0, 0);
      }
    }

    // online softmax (row = g*4 + j, col = n*16 + c)
    float sc[4][4], mx[4];
#pragma unroll
    for (int j = 0; j < 4; ++j) mx[j] = -1e30f;
#pragma unroll
    for (int n = 0; n < 4; ++n)
#pragma unroll
      for (int j = 0; j < 4; ++j) {
        float v = accs[n][j] * ASCALE + ((sgn[n] == msg[j]) ? 0.f : -1e9f);
        sc[n][j] = v;
        mx[j] = fmaxf(mx[j], v);
      }
#pragma unroll
    for (int j = 0; j < 4; ++j) {
      mx[j] = fmaxf(mx[j], __shfl_xor(mx[j], 1));
      mx[j] = fmaxf(mx[j], __shfl_xor(mx[j], 2));
      mx[j] = fmaxf(mx[j], __shfl_xor(mx[j], 4));
      mx[j] = fmaxf(mx[j], __shfl_xor(mx[j], 8));
    }
    float alpha[4], rs[4];
#pragma unroll
    for (int j = 0; j < 4; ++j) {
      float mn = fmaxf(mj[j], mx[j]);
      alpha[j] = __expf(mj[j] - mn);
      mj[j] = mn;
      rs[j] = 0.f;
    }
    float pv[4][4];
#pragma unroll
    for (int n = 0; n < 4; ++n)
#pragma unroll
      for (int j = 0; j < 4; ++j) {
        float p = __expf(sc[n][j] - mj[j]);
        pv[n][j] = p;
        rs[j] += p;
      }
#pragma unroll
    for (int j = 0; j < 4; ++j) {
      rs[j] += __shfl_xor(rs[j], 1);
      rs[j] += __shfl_xor(rs[j], 2);
      rs[j] += __shfl_xor(rs[j], 4);
      rs[j] += __shfl_xor(rs[j], 8);
      lj[j] = lj[j] * alpha[j] + rs[j];
    }
    // write P (bf16) to this wave's private LDS slice
#pragma unroll
    for (int n = 0; n < 4; ++n)
#pragma unroll
      for (int j = 0; j < 4; ++j)
        Ps[wv][(g * 4 + j) * 72 + n * 16 + c] = f2b(pv[n][j]);

    // rescale O accumulators
#pragma unroll
    for (int n = 0; n < 5; ++n)
#pragma unroll
      for (int j = 0; j < 4; ++j) acco[n][j] *= alpha[j];

    // same-wave LDS write->read ordering
    asm volatile("s_waitcnt lgkmcnt(0)" ::: "memory");
    __builtin_amdgcn_sched_barrier(0);

    // PV: 5 d-frags x 2 k-steps
#pragma unroll
    for (int ks = 0; ks < 2; ++ks) {
      s8v pa = *reinterpret_cast<const s8v*>(&Ps[wv][c * 72 + ks * 32 + g * 8]);
#pragma unroll
      for (int n = 0; n < 5; ++n) {
        s8v vb = *reinterpret_cast<const s8v*>(&Vt[(n * 16 + c) * 72 + ks * 32 + g * 8]);
        acco[n] = __builtin_amdgcn_mfma_f32_16x16x32_bf16(pa, vb, acco[n], 0, 0, 0);
      }
    }
  }

  // epilogue: divide by l, store (row = g*4+j, col = n*16+c)
  float rden[4];
#pragma unroll
  for (int j = 0; j < 4; ++j) rden[j] = 1.f / lj[j];
#pragma unroll
  for (int n = 0; n < 5; ++n) {
    int col = n * 16 + c;
    if (col < HD) {
#pragma unroll
      for (int j = 0; j < 4; ++j) {
        int row = q0 + wv * 16 + g * 4 + j;
        oout[(size_t)row * HDIM + hh * HD + col] = acco[n][j] * rden[j];
      }
    }
  }
}

// ---------- launch ----------
extern "C" void kernel_launch(void* const* d_in, const int* in_sizes, int n_in,
                              void* d_out, int out_size, void* d_ws, size_t ws_size,
                              hipStream_t stream)
{
  (void)n_in; (void)out_size; (void)ws_size;
  const float* pix    = (const float*)d_in[0];
  const int*   cu     = (const int*)d_in[1];
  const int    n_cu   = in_sizes[1];
  const float* conv_w = (const float*)d_in[2];
  const float* conv_b = (const float*)d_in[3];
  const float* pos_tab= (const float*)d_in[4];
  const float* ln1_w  = (const float*)d_in[5];
  const float* ln1_b  = (const float*)d_in[6];
  const float* ln2_w  = (const float*)d_in[7];
  const float* ln2_b  = (const float*)d_in[8];
  const float* qkv_w  = (const float*)d_in[9];
  const float* qkv_b  = (const float*)d_in[10];
  const float* proj_w = (const float*)d_in[11];
  const float* proj_b = (const float*)d_in[12];
  const float* fc1_w  = (const float*)d_in[13];
  const float* fc1_b  = (const float*)d_in[14];
  const float* fc2_w  = (const float*)d_in[15];
  const float* fc2_b  = (const float*)d_in[16];
  const float* mn_w   = (const float*)d_in[17];
  const float* mn_b   = (const float*)d_in[18];
  const float* mf1_w  = (const float*)d_in[19];
  const float* mf1_b  = (const float*)d_in[20];
  const float* mf2_w  = (const float*)d_in[21];
  const float* mf2_b  = (const float*)d_in[22];
  float* out = (float*)d_out;

  float* x    = (float*)d_ws;
  float* h    = x + (size_t)S * HDIM;
  float* A    = h + (size_t)S * HDIM;
  float* cosT = A + (size_t)S * INTERP;
  float* sinT = cosT + (size_t)S * 36;
  int*   seg  = (int*)(sinT + (size_t)S * 36);

  gemm_bf16_kernel<<<dim3(HDIM / 128, S / 128), 256, 0, stream>>>(
      pix, conv_w, conv_b, nullptr, x, S, HDIM, KIN, KIN, KIN, KIN, HDIM, 0);
  add_pos_kernel<<<S, 256, 0, stream>>>(x, pos_tab);
  rope_tables_kernel<<<S, 64, 0, stream>>>(cosT, sinT);
  seg_kernel<<<(S + 255) / 256, 256, 0, stream>>>(cu, n_cu, seg);

  for (int layer = 0; layer < DEPTH; ++layer) {
    ln_kernel<<<S, 256, 0, stream>>>(x, ln1_w + layer * HDIM, ln1_b + layer * HDIM, h);
    gemm_bf16_kernel<<<dim3(3456 / 128, S / 128), 256, 0, stream>>>(
        h, qkv_w + (size_t)layer * 3456 * HDIM, qkv_b + layer * 3456, nullptr, A,
        S, 3456, HDIM, HDIM, HDIM, HDIM, 3456, 0);
    rope_kernel<<<(S * 2 * NHEAD * 36) / 256, 256, 0, stream>>>(A, cosT, sinT);
    flash_mfma_kernel<<<dim3(S / 64, NHEAD), 256, 0, stream>>>(A, h, seg);
    gemm_bf16_kernel<<<dim3(HDIM / 128, S / 128), 256, 0, stream>>>(
        h, proj_w + (size_t)layer * HDIM * HDIM, proj_b + layer * HDIM, x, x,
        S, HDIM, HDIM, HDIM, HDIM, HDIM, HDIM, 0);
    ln_kernel<<<S, 256, 0, stream>>>(x, ln2_w + layer * HDIM, ln2_b + layer * HDIM, h);
    gemm_bf16_kernel<<<dim3(INTERP / 128, S / 128), 256, 0, stream>>>(
        h, fc1_w + (size_t)layer * INTER * HDIM, fc1_b + layer * INTER, nullptr, A,
        S, INTER, HDIM, HDIM, HDIM, HDIM, INTERP, 1);
    gemm_bf16_kernel<<<dim3(HDIM / 128, S / 128), 256, 0, stream>>>(
        A, fc2_w + (size_t)layer * HDIM * INTER, fc2_b + layer * HDIM, x, x,
        S, HDIM, INTERP, INTER, INTERP, INTER, HDIM, 0);
  }

  ln_kernel<<<S, 256, 0, stream>>>(x, mn_w, mn_b, h);
  gemm_bf16_kernel<<<dim3(MERGED / 128, (576 + 127) / 128), 256, 0, stream>>>(
      h, mf1_w, mf1_b, nullptr, A, 576, MERGED, MERGED, MERGED, MERGED, MERGED, MERGED, 1);
  gemm_nt_kernel<<<dim3(OUTD / 64, 576 / 64), 256, 0, stream>>>(
      A, mf2_w, mf2_b, nullptr, out, 576, OUTD, MERGED, 0);
}

// Round 5
// 2332.187 us; speedup vs baseline: 5.9455x; 2.0905x over previous
//
#include <hip/hip_runtime.h>
#include <hip/hip_bf16.h>
#include <math.h>

#define S 2304
#define HDIM 1152
#define NHEAD 16
#define HD 72
#define INTER 4304
#define INTERP 4352   // INTER padded to multiple of 128
#define DEPTH 4
#define MERGED 4608
#define OUTD 2048
#define KIN 1536

typedef float f4 __attribute__((ext_vector_type(4)));
typedef short s8v __attribute__((ext_vector_type(8)));

// ---------- helpers ----------
__device__ __forceinline__ int pos_id_of(int s) {
  int a = s / 96;
  int r = s % 96;
  int b = r >> 2;
  int c = (r >> 1) & 1;
  int d = r & 1;
  return a * 96 + c * 48 + b * 2 + d;
}

__device__ __forceinline__ float gelu_f(float v) {
  const float c = 0.7978845608028654f;
  float t = tanhf(c * (v + 0.044715f * v * v * v));
  return 0.5f * v * (1.f + t);
}

__device__ __forceinline__ unsigned short f2b(float f) {
  unsigned int u = __float_as_uint(f);
  u += 0x7fffu + ((u >> 16) & 1u);
  return (unsigned short)(u >> 16);
}
__device__ __forceinline__ float b2f(unsigned short u) {
  return __uint_as_float(((unsigned int)u) << 16);
}

__device__ __forceinline__ void gload16(const void* g, void* l) {
  __builtin_amdgcn_global_load_lds(
      (const __attribute__((address_space(1))) void*)g,
      (__attribute__((address_space(3))) void*)l, 16, 0, 0);
}

// ---------- fp32 -> bf16 convert (with K padding) ----------
__global__ void __launch_bounds__(256) cvt_kernel(
    const float* __restrict__ src, unsigned short* __restrict__ dst,
    int N, int Ksrc, int Kdst)
{
  int idx = blockIdx.x * 256 + threadIdx.x;
  int kc = Kdst >> 3;
  if (idx >= N * kc) return;
  int r = idx / kc;
  int c8 = (idx % kc) << 3;
  const float* sp = src + (size_t)r * Ksrc + c8;
  unsigned short outv[8];
#pragma unroll
  for (int e = 0; e < 8; ++e)
    outv[e] = (c8 + e < Ksrc) ? f2b(sp[e]) : (unsigned short)0;
  *(uint4*)(dst + (size_t)r * Kdst + c8) = *(uint4*)outv;
}

// ---------- bf16 MFMA NT GEMM (global_load_lds + double-buffered LDS) ----------
__global__ void __launch_bounds__(256) gemm_bf16_kernel(
    const unsigned short* __restrict__ A, const unsigned short* __restrict__ B,
    const float* __restrict__ bias, const float* __restrict__ resid,
    void* __restrict__ Cout, int M, int Nreal, int K,
    int lda, int ldb, int ldc, int act, int outbf)
{
  __shared__ unsigned short Asm[2][128 * 32];
  __shared__ unsigned short Bsm[2][128 * 32];
  const int tid = threadIdx.x;
  const int lane = tid & 63;
  const int wv = tid >> 6;
  const int wr = wv >> 1, wc = wv & 1;
  const int bm = blockIdx.y * 128, bn = blockIdx.x * 128;
  const int g8 = (lane >> 4) << 3;
  const int lr = lane & 15;

  // staging geometry: wave wv covers rows wv*32..wv*32+31 in two 16-row issues
  const int srow = wv * 32 + (lane >> 2);
  const int kcol = (lane & 3) << 3;
  int ar0 = bm + srow;      if (ar0 >= M) ar0 = M - 1;
  int ar1 = bm + srow + 16; if (ar1 >= M) ar1 = M - 1;
  int br0 = bn + srow;      if (br0 >= Nreal) br0 = Nreal - 1;
  int br1 = bn + srow + 16; if (br1 >= Nreal) br1 = Nreal - 1;
  const unsigned short* Ag0 = A + (size_t)ar0 * lda + kcol;
  const unsigned short* Ag1 = A + (size_t)ar1 * lda + kcol;
  const unsigned short* Bg0 = B + (size_t)br0 * ldb + kcol;
  const unsigned short* Bg1 = B + (size_t)br1 * ldb + kcol;

  f4 acc[4][4];
#pragma unroll
  for (int m = 0; m < 4; ++m)
#pragma unroll
    for (int n = 0; n < 4; ++n) { acc[m][n].x = 0.f; acc[m][n].y = 0.f; acc[m][n].z = 0.f; acc[m][n].w = 0.f; }

  const int nt = K >> 5;
  gload16(Ag0, &Asm[0][(wv * 32) * 32]);
  gload16(Ag1, &Asm[0][(wv * 32 + 16) * 32]);
  gload16(Bg0, &Bsm[0][(wv * 32) * 32]);
  gload16(Bg1, &Bsm[0][(wv * 32 + 16) * 32]);
  asm volatile("s_waitcnt vmcnt(0)" ::: "memory");
  __syncthreads();

  int cur = 0;
  for (int t = 0; t < nt; ++t) {
    if (t + 1 < nt) {
      int ko = (t + 1) << 5;
      gload16(Ag0 + ko, &Asm[cur ^ 1][(wv * 32) * 32]);
      gload16(Ag1 + ko, &Asm[cur ^ 1][(wv * 32 + 16) * 32]);
      gload16(Bg0 + ko, &Bsm[cur ^ 1][(wv * 32) * 32]);
      gload16(Bg1 + ko, &Bsm[cur ^ 1][(wv * 32 + 16) * 32]);
    }
    s8v af[4], bf[4];
#pragma unroll
    for (int m = 0; m < 4; ++m)
      af[m] = *(const s8v*)&Asm[cur][(wr * 64 + m * 16 + lr) * 32 + g8];
#pragma unroll
    for (int n = 0; n < 4; ++n)
      bf[n] = *(const s8v*)&Bsm[cur][(wc * 64 + n * 16 + lr) * 32 + g8];
#pragma unroll
    for (int m = 0; m < 4; ++m)
#pragma unroll
      for (int n = 0; n < 4; ++n)
        acc[m][n] = __builtin_amdgcn_mfma_f32_16x16x32_bf16(af[m], bf[n], acc[m][n], 0, 0, 0);
    asm volatile("s_waitcnt vmcnt(0)" ::: "memory");
    __syncthreads();
    cur ^= 1;
  }

  const int g4 = (lane >> 4) << 2;
#pragma unroll
  for (int m = 0; m < 4; ++m) {
    int r = bm + wr * 64 + m * 16 + g4;
#pragma unroll
    for (int n = 0; n < 4; ++n) {
      int cidx = bn + wc * 64 + n * 16 + lr;
      float bb = (cidx < Nreal) ? bias[cidx] : 0.f;
#pragma unroll
      for (int j = 0; j < 4; ++j) {
        int rr = r + j;
        if (rr < M) {
          float v = acc[m][n][j] + bb;
          if (act) v = gelu_f(v);
          if (cidx >= Nreal) v = 0.f;
          if (resid) v += resid[(size_t)rr * ldc + cidx];
          if (outbf) ((unsigned short*)Cout)[(size_t)rr * ldc + cidx] = f2b(v);
          else       ((float*)Cout)[(size_t)rr * ldc + cidx] = v;
        }
      }
    }
  }
}

// ---------- LayerNorm (fp32 in, bf16 out) ----------
__global__ void __launch_bounds__(256) ln_kernel(const float* __restrict__ xin,
    const float* __restrict__ w, const float* __restrict__ b, unsigned short* __restrict__ out)
{
  __shared__ float red[8];
  const int row = blockIdx.x;
  const float* xr = xin + (size_t)row * HDIM;
  float s = 0.f;
  for (int i = threadIdx.x; i < HDIM; i += 256) s += xr[i];
#pragma unroll
  for (int off = 32; off > 0; off >>= 1) s += __shfl_down(s, off);
  if ((threadIdx.x & 63) == 0) red[threadIdx.x >> 6] = s;
  __syncthreads();
  float mean = (red[0] + red[1] + red[2] + red[3]) * (1.f / HDIM);
  float s2 = 0.f;
  for (int i = threadIdx.x; i < HDIM; i += 256) { float d = xr[i] - mean; s2 += d * d; }
#pragma unroll
  for (int off = 32; off > 0; off >>= 1) s2 += __shfl_down(s2, off);
  __syncthreads();
  if ((threadIdx.x & 63) == 0) red[threadIdx.x >> 6] = s2;
  __syncthreads();
  float var = (red[0] + red[1] + red[2] + red[3]) * (1.f / HDIM);
  float rstd = rsqrtf(var + 1e-6f);
  for (int i = threadIdx.x; i < HDIM; i += 256)
    out[(size_t)row * HDIM + i] = f2b(w[i] * ((xr[i] - mean) * rstd) + b[i]);
}

// ---------- pos embedding add ----------
__global__ void __launch_bounds__(256) add_pos_kernel(float* __restrict__ x, const float* __restrict__ pos_tab)
{
  int s = blockIdx.x;
  int pid = pos_id_of(s);
  const float* pr = pos_tab + (size_t)pid * HDIM;
  float* xr = x + (size_t)s * HDIM;
  for (int i = threadIdx.x; i < HDIM; i += 256) xr[i] += pr[i];
}

// ---------- RoPE tables ----------
__global__ void rope_tables_kernel(float* __restrict__ cosT, float* __restrict__ sinT)
{
  int s = blockIdx.x;
  int j = threadIdx.x;
  if (j >= 36) return;
  int pid = pos_id_of(s);
  float hp = (float)(pid / 48);
  float wp = (float)(pid % 48);
  int f = (j < 18) ? j : (j - 18);
  float inv = powf(10000.f, -(2.f * (float)f) / 36.f);
  float ang = ((j < 18) ? hp : wp) * inv;
  cosT[s * 36 + j] = cosf(ang);
  sinT[s * 36 + j] = sinf(ang);
}

// ---------- seg ids ----------
__global__ void seg_kernel(const int* __restrict__ cu, int n_cu, int* __restrict__ seg)
{
  int i = blockIdx.x * 256 + threadIdx.x;
  if (i >= S) return;
  int s = 0;
  for (int t = 0; t < n_cu; ++t) s += (cu[t] <= i) ? 1 : 0;
  seg[i] = s;
}

// ---------- RoPE apply (bf16 in/out, fp32 math) ----------
__global__ void __launch_bounds__(256) rope_kernel(unsigned short* __restrict__ qkv,
    const float* __restrict__ cosT, const float* __restrict__ sinT)
{
  int idx = blockIdx.x * 256 + threadIdx.x;
  int d = idx % 36; int t = idx / 36;
  int hh = t % NHEAD; t /= NHEAD;
  int qk = t & 1; int s = t >> 1;
  unsigned short* base = qkv + (size_t)s * 3456 + qk * 1152 + hh * 72;
  float c = cosT[s * 36 + d], sn = sinT[s * 36 + d];
  float x0 = b2f(base[d]), x1 = b2f(base[d + 36]);
  base[d] = f2b(x0 * c - x1 * sn);
  base[d + 36] = f2b(x1 * c + x0 * sn);
}

// ---------- MFMA flash attention (bf16 qkv in, bf16 out) ----------
#define KT 64
#define ASCALE 0.11785113019775793f

__global__ void __launch_bounds__(256) flash_mfma_kernel(
    const unsigned short* __restrict__ qkv, unsigned short* __restrict__ oout,
    const int* __restrict__ seg)
{
  __shared__ __align__(16) unsigned short Ks[64 * 104];
  __shared__ __align__(16) unsigned short Vt[80 * 72];
  __shared__ __align__(16) unsigned short Ps[4][16 * 72];

  const int tid = threadIdx.x;
  const int lane = tid & 63;
  const int wv = tid >> 6;
  const int g = lane >> 4;
  const int c = lane & 15;
  const int hh = blockIdx.y;
  const int q0 = blockIdx.x * 64;

  // zero pads: Ks cols 72..95 (ALL of them — MFMA ks=2 reads cols 64..95), Vt rows 72..79
  for (int i = tid; i < 64 * 12; i += 256) {
    int r = i / 12, cc = i % 12;
    *(unsigned int*)&Ks[r * 104 + 72 + cc * 2] = 0u;
  }
  for (int i = tid; i < 288; i += 256)
    *(unsigned int*)&Vt[72 * 72 + i * 2] = 0u;

  // Q fragments straight from bf16 global
  s8v qf[3];
  {
    const int qrow = q0 + wv * 16 + c;
    const unsigned short* qb = qkv + (size_t)qrow * 3456 + hh * HD;
#pragma unroll
    for (int ks = 0; ks < 3; ++ks) {
      int k = ks * 32 + g * 8;
      if (k <= 64) qf[ks] = *(const s8v*)(qb + k);
      else {
        s8v z;
#pragma unroll
        for (int t = 0; t < 8; ++t) z[t] = 0;
        qf[ks] = z;
      }
    }
  }

  int msg[4];
#pragma unroll
  for (int j = 0; j < 4; ++j) msg[j] = seg[q0 + wv * 16 + g * 4 + j];

  float mj[4], lj[4];
#pragma unroll
  for (int j = 0; j < 4; ++j) { mj[j] = -1e30f; lj[j] = 0.f; }
  f4 acco[5];
#pragma unroll
  for (int n = 0; n < 5; ++n) { acco[n].x = 0.f; acco[n].y = 0.f; acco[n].z = 0.f; acco[n].w = 0.f; }

  for (int k0 = 0; k0 < S; k0 += KT) {
    __syncthreads();
    // stage K tile (bf16 copy, 16B chunks)
    for (int idx = tid; idx < 576; idx += 256) {
      int r = idx / 9, c16 = idx % 9;
      uint4 v = *(const uint4*)(qkv + (size_t)(k0 + r) * 3456 + 1152 + hh * HD + c16 * 8);
      *(uint4*)&Ks[r * 104 + c16 * 8] = v;
    }
    // stage V transposed (k-major write pattern)
    for (int idx = tid; idx < 576; idx += 256) {
      int r = idx & 63, c16 = idx >> 6;
      unsigned short vv[8];
      *(uint4*)vv = *(const uint4*)(qkv + (size_t)(k0 + r) * 3456 + 2304 + hh * HD + c16 * 8);
#pragma unroll
      for (int e = 0; e < 8; ++e) Vt[(c16 * 8 + e) * 72 + r] = vv[e];
    }
    __syncthreads();

    int sgn[4];
#pragma unroll
    for (int n = 0; n < 4; ++n) sgn[n] = seg[k0 + n * 16 + c];

    f4 accs[4];
#pragma unroll
    for (int n = 0; n < 4; ++n) { accs[n].x = 0.f; accs[n].y = 0.f; accs[n].z = 0.f; accs[n].w = 0.f; }
#pragma unroll
    for (int ks = 0; ks < 3; ++ks) {
#pragma unroll
      for (int n = 0; n < 4; ++n) {
        s8v bk = *(const s8v*)&Ks[(n * 16 + c) * 104 + ks * 32 + g * 8];
        accs[n] = __builtin_amdgcn_mfma_f32_16x16x32_bf16(qf[ks], bk, accs[n], 0, 0, 0);
      }
    }

    float sc[4][4], mx[4];
#pragma unroll
    for (int j = 0; j < 4; ++j) mx[j] = -1e30f;
#pragma unroll
    for (int n = 0; n < 4; ++n)
#pragma unroll
      for (int j = 0; j < 4; ++j) {
        float v = accs[n][j] * ASCALE + ((sgn[n] == msg[j]) ? 0.f : -1e9f);
        sc[n][j] = v;
        mx[j] = fmaxf(mx[j], v);
      }
#pragma unroll
    for (int j = 0; j < 4; ++j) {
      mx[j] = fmaxf(mx[j], __shfl_xor(mx[j], 1));
      mx[j] = fmaxf(mx[j], __shfl_xor(mx[j], 2));
      mx[j] = fmaxf(mx[j], __shfl_xor(mx[j], 4));
      mx[j] = fmaxf(mx[j], __shfl_xor(mx[j], 8));
    }
    float alpha[4], rs[4];
#pragma unroll
    for (int j = 0; j < 4; ++j) {
      float mn = fmaxf(mj[j], mx[j]);
      alpha[j] = __expf(mj[j] - mn);
      mj[j] = mn;
      rs[j] = 0.f;
    }
    float pv[4][4];
#pragma unroll
    for (int n = 0; n < 4; ++n)
#pragma unroll
      for (int j = 0; j < 4; ++j) {
        float p = __expf(sc[n][j] - mj[j]);
        pv[n][j] = p;
        rs[j] += p;
      }
#pragma unroll
    for (int j = 0; j < 4; ++j) {
      rs[j] += __shfl_xor(rs[j], 1);
      rs[j] += __shfl_xor(rs[j], 2);
      rs[j] += __shfl_xor(rs[j], 4);
      rs[j] += __shfl_xor(rs[j], 8);
      lj[j] = lj[j] * alpha[j] + rs[j];
    }
#pragma unroll
    for (int n = 0; n < 4; ++n)
#pragma unroll
      for (int j = 0; j < 4; ++j)
        Ps[wv][(g * 4 + j) * 72 + n * 16 + c] = f2b(pv[n][j]);

#pragma unroll
    for (int n = 0; n < 5; ++n)
#pragma unroll
      for (int j = 0; j < 4; ++j) acco[n][j] *= alpha[j];

    asm volatile("s_waitcnt lgkmcnt(0)" ::: "memory");
    __builtin_amdgcn_sched_barrier(0);

#pragma unroll
    for (int ks = 0; ks < 2; ++ks) {
      s8v pa = *(const s8v*)&Ps[wv][c * 72 + ks * 32 + g * 8];
#pragma unroll
      for (int n = 0; n < 5; ++n) {
        s8v vb = *(const s8v*)&Vt[(n * 16 + c) * 72 + ks * 32 + g * 8];
        acco[n] = __builtin_amdgcn_mfma_f32_16x16x32_bf16(pa, vb, acco[n], 0, 0, 0);
      }
    }
  }

  float rden[4];
#pragma unroll
  for (int j = 0; j < 4; ++j) rden[j] = 1.f / lj[j];
#pragma unroll
  for (int n = 0; n < 5; ++n) {
    int col = n * 16 + c;
    if (col < HD) {
#pragma unroll
      for (int j = 0; j < 4; ++j) {
        int row = q0 + wv * 16 + g * 4 + j;
        oout[(size_t)row * HDIM + hh * HD + col] = f2b(acco[n][j] * rden[j]);
      }
    }
  }
}

// ---------- launch ----------
extern "C" void kernel_launch(void* const* d_in, const int* in_sizes, int n_in,
                              void* d_out, int out_size, void* d_ws, size_t ws_size,
                              hipStream_t stream)
{
  (void)n_in; (void)out_size; (void)ws_size;
  const float* pix    = (const float*)d_in[0];
  const int*   cu     = (const int*)d_in[1];
  const int    n_cu   = in_sizes[1];
  const float* conv_w = (const float*)d_in[2];
  const float* conv_b = (const float*)d_in[3];
  const float* pos_tab= (const float*)d_in[4];
  const float* ln1_w  = (const float*)d_in[5];
  const float* ln1_b  = (const float*)d_in[6];
  const float* ln2_w  = (const float*)d_in[7];
  const float* ln2_b  = (const float*)d_in[8];
  const float* qkv_w  = (const float*)d_in[9];
  const float* qkv_b  = (const float*)d_in[10];
  const float* proj_w = (const float*)d_in[11];
  const float* proj_b = (const float*)d_in[12];
  const float* fc1_w  = (const float*)d_in[13];
  const float* fc1_b  = (const float*)d_in[14];
  const float* fc2_w  = (const float*)d_in[15];
  const float* fc2_b  = (const float*)d_in[16];
  const float* mn_w   = (const float*)d_in[17];
  const float* mn_b   = (const float*)d_in[18];
  const float* mf1_w  = (const float*)d_in[19];
  const float* mf1_b  = (const float*)d_in[20];
  const float* mf2_w  = (const float*)d_in[21];
  const float* mf2_b  = (const float*)d_in[22];
  float* out = (float*)d_out;

  // workspace layout (all 16B-aligned); pix_bf aliases A_bf (disjoint lifetimes)
  float*    x      = (float*)d_ws;                                        // S*HDIM f32
  unsigned short* h_bf   = (unsigned short*)(x + (size_t)S * HDIM);       // S*HDIM bf16
  unsigned short* qkv_bf = h_bf + (size_t)S * HDIM;                       // S*3456 bf16
  unsigned short* A_bf   = qkv_bf + (size_t)S * 3456;                     // S*INTERP bf16
  unsigned short* Wbuf   = A_bf + (size_t)S * INTERP;                     // 4608*4608 bf16
  float*    cosT   = (float*)(Wbuf + (size_t)MERGED * MERGED);
  float*    sinT   = cosT + (size_t)S * 36;
  int*      seg    = (int*)(sinT + (size_t)S * 36);
  unsigned short* pix_bf = A_bf;                                          // alias

  auto cvt = [&](const float* src, unsigned short* dst, int N, int Ksrc, int Kdst) {
    int total = N * (Kdst >> 3);
    cvt_kernel<<<(total + 255) / 256, 256, 0, stream>>>(src, dst, N, Ksrc, Kdst);
  };
  auto gemm = [&](const unsigned short* A, const unsigned short* B, const float* bias,
                  const float* resid, void* C, int M, int N, int K,
                  int lda, int ldb, int ldc, int act, int outbf) {
    gemm_bf16_kernel<<<dim3((N + 127) / 128, (M + 127) / 128), 256, 0, stream>>>(
        A, B, bias, resid, C, M, N, K, lda, ldb, ldc, act, outbf);
  };

  // patch embed
  cvt(pix, pix_bf, S, KIN, KIN);
  cvt(conv_w, Wbuf, HDIM, KIN, KIN);
  gemm(pix_bf, Wbuf, conv_b, nullptr, x, S, HDIM, KIN, KIN, KIN, HDIM, 0, 0);
  add_pos_kernel<<<S, 256, 0, stream>>>(x, pos_tab);
  rope_tables_kernel<<<S, 64, 0, stream>>>(cosT, sinT);
  seg_kernel<<<(S + 255) / 256, 256, 0, stream>>>(cu, n_cu, seg);

  for (int layer = 0; layer < DEPTH; ++layer) {
    ln_kernel<<<S, 256, 0, stream>>>(x, ln1_w + layer * HDIM, ln1_b + layer * HDIM, h_bf);
    cvt(qkv_w + (size_t)layer * 3456 * HDIM, Wbuf, 3456, HDIM, HDIM);
    gemm(h_bf, Wbuf, qkv_b + layer * 3456, nullptr, qkv_bf, S, 3456, HDIM, HDIM, HDIM, 3456, 0, 1);
    rope_kernel<<<(S * 2 * NHEAD * 36) / 256, 256, 0, stream>>>(qkv_bf, cosT, sinT);
    flash_mfma_kernel<<<dim3(S / 64, NHEAD), 256, 0, stream>>>(qkv_bf, h_bf, seg);
    cvt(proj_w + (size_t)layer * HDIM * HDIM, Wbuf, HDIM, HDIM, HDIM);
    gemm(h_bf, Wbuf, proj_b + layer * HDIM, x, x, S, HDIM, HDIM, HDIM, HDIM, HDIM, 0, 0);
    ln_kernel<<<S, 256, 0, stream>>>(x, ln2_w + layer * HDIM, ln2_b + layer * HDIM, h_bf);
    cvt(fc1_w + (size_t)layer * INTER * HDIM, Wbuf, INTER, HDIM, HDIM);
    gemm(h_bf, Wbuf, fc1_b + layer * INTER, nullptr, A_bf, S, INTER, HDIM, HDIM, HDIM, INTERP, 1, 1);
    cvt(fc2_w + (size_t)layer * HDIM * INTER, Wbuf, HDIM, INTER, INTERP);
    gemm(A_bf, Wbuf, fc2_b + layer * HDIM, x, x, S, HDIM, INTERP, INTERP, INTERP, HDIM, 0, 0);
  }

  // merger
  ln_kernel<<<S, 256, 0, stream>>>(x, mn_w, mn_b, h_bf);   // viewed (576, 4608)
  cvt(mf1_w, Wbuf, MERGED, MERGED, MERGED);
  gemm(h_bf, Wbuf, mf1_b, nullptr, A_bf, 576, MERGED, MERGED, MERGED, MERGED, MERGED, 1, 1);
  cvt(mf2_w, Wbuf, OUTD, MERGED, MERGED);
  gemm(A_bf, Wbuf, mf2_b, nullptr, out, 576, OUTD, MERGED, MERGED, MERGED, OUTD, 0, 0);
}